// Round 1
// baseline (10.441 us; speedup 1.0000x reference)
//
#include <hip/hip_runtime.h>

// ScaledThresholdsQuantization4d: B=8, C=64, H=56, W=56, 255 sorted integer
// thresholds per channel in [-192, 191].
// out = sign>0 ? #{t < floor(x)} : 255 - #{t < floor(x)}, as float32.
//
// Strategy: per-channel 385-entry LUT over clamp(floor(x), -192, 192),
// built in LDS per block via binary search, then stream the (b,c) slice
// as float4.

#define C_DIM 64
#define NTH 255
#define LUT_MIN (-192)
#define LUT_SIZE 385            // q in [-192 .. 192]
#define SLICE 3136              // 56*56
#define VEC4_PER_SLICE 784      // 3136/4 = 256*3 + 16

__global__ __launch_bounds__(256)
void stq4d_kernel(const float* __restrict__ x,
                  const float* __restrict__ thresholds,
                  const int* __restrict__ signs,
                  float* __restrict__ out)
{
    __shared__ float t_sh[NTH];
    __shared__ float lut[LUT_SIZE];   // sign-resolved count, as float

    const int bc  = blockIdx.x;       // b*64 + c, 0..511
    const int c   = bc & (C_DIM - 1);
    const int tid = threadIdx.x;

    // Stage this channel's sorted thresholds.
    if (tid < NTH) t_sh[tid] = thresholds[c * NTH + tid];
    const int sign = signs[c];
    __syncthreads();

    // Build LUT: lut[i] = resolve(#{t < (i + LUT_MIN)}).
    // Fixed 8-iter binary search: interval sizes 255->127->63->31->15->7->3->1->0,
    // lo<hi holds at every iteration start, mid <= 254 (no OOB).
    for (int i = tid; i < LUT_SIZE; i += 256) {
        const float v = (float)(i + LUT_MIN);
        int lo = 0, hi = NTH;
        #pragma unroll
        for (int s = 0; s < 8; ++s) {
            const int mid = (lo + hi) >> 1;
            if (t_sh[mid] < v) lo = mid + 1; else hi = mid;
        }
        const int pos = lo;
        lut[i] = (float)(sign > 0 ? pos : (NTH - pos));
    }
    __syncthreads();

    const float4* __restrict__ xv = (const float4*)(x + (size_t)bc * SLICE);
    float4* __restrict__ ov       = (float4*)(out + (size_t)bc * SLICE);

    // 784 = 3*256 + 16. Issue the 3 main loads up front (independent, in flight).
    const float4 v0 = xv[tid];
    const float4 v1 = xv[tid + 256];
    const float4 v2 = xv[tid + 512];

    #define LOOKUP(f) lut[(int)fminf(fmaxf(floorf(f), -192.0f), 192.0f) + 192]
    float4 r0, r1, r2;
    r0.x = LOOKUP(v0.x); r0.y = LOOKUP(v0.y); r0.z = LOOKUP(v0.z); r0.w = LOOKUP(v0.w);
    r1.x = LOOKUP(v1.x); r1.y = LOOKUP(v1.y); r1.z = LOOKUP(v1.z); r1.w = LOOKUP(v1.w);
    r2.x = LOOKUP(v2.x); r2.y = LOOKUP(v2.y); r2.z = LOOKUP(v2.z); r2.w = LOOKUP(v2.w);
    ov[tid]       = r0;
    ov[tid + 256] = r1;
    ov[tid + 512] = r2;

    if (tid < VEC4_PER_SLICE - 768) {   // tail: 16 vec4
        const float4 v3 = xv[tid + 768];
        float4 r3;
        r3.x = LOOKUP(v3.x); r3.y = LOOKUP(v3.y); r3.z = LOOKUP(v3.z); r3.w = LOOKUP(v3.w);
        ov[tid + 768] = r3;
    }
    #undef LOOKUP
}

extern "C" void kernel_launch(void* const* d_in, const int* in_sizes, int n_in,
                              void* d_out, int out_size, void* d_ws, size_t ws_size,
                              hipStream_t stream) {
    const float* x          = (const float*)d_in[0];
    const float* thresholds = (const float*)d_in[1];
    const int*   signs      = (const int*)d_in[2];
    float*       out        = (float*)d_out;

    // 8*64 = 512 blocks, one (b,c) slice of 3136 elements each.
    stq4d_kernel<<<512, 256, 0, stream>>>(x, thresholds, signs, out);
}

// Round 3
// 10.368 us; speedup vs baseline: 1.0070x; 1.0070x over previous
//
#include <hip/hip_runtime.h>

// ScaledThresholdsQuantization4d: B=8, C=64, H=56, W=56, 255 sorted integer
// thresholds per channel in [-192, 191].
// out = sign>0 ? #{t < floor(x)} : 255 - #{t < floor(x)}, as float32.
//
// R3 = R2 with the NT-store type fixed (clang native vector, not HIP_vector_type).
// Structure: per-(b,c) block. Issue ALL x loads up front (12.25 float4/thread),
// build the 385-entry LUT via O(1)-depth range-fill (thread j owns the integer
// interval (t[j-1], t[j]] -> pos=j), one barrier, lookup + NT store.

#define C_DIM 64
#define NTH 255
#define LUT_SIZE 385            // q in [-192 .. 192]
#define SLICE 3136              // 56*56 = 784 float4 = 3*256 + 16

typedef float vfloat4 __attribute__((ext_vector_type(4)));

__global__ __launch_bounds__(256)
void stq4d_kernel(const float* __restrict__ x,
                  const float* __restrict__ thresholds,
                  const int* __restrict__ signs,
                  float* __restrict__ out)
{
    __shared__ float lut[LUT_SIZE];   // sign-resolved count, as float

    const int bc  = blockIdx.x;       // b*64 + c
    const int c   = bc & (C_DIM - 1);
    const int tid = threadIdx.x;

    const vfloat4* __restrict__ xv = (const vfloat4*)(x + (size_t)bc * SLICE);
    vfloat4* __restrict__ ov       = (vfloat4*)(out + (size_t)bc * SLICE);

    // 1) Issue the whole slice's loads first — HBM latency hides under the
    //    LUT build below (the barrier's vmcnt drain comes after that work).
    const vfloat4 v0 = xv[tid];
    const vfloat4 v1 = xv[tid + 256];
    const vfloat4 v2 = xv[tid + 512];
    vfloat4 v3;
    if (tid < 16) v3 = xv[tid + 768];

    // 2) Range-fill LUT. Thread j covers integer q with t[j-1] < q <= t[j]
    //    (t[-1] = -inf, t[255] = +inf): there #{t < q} = j exactly (holds
    //    with duplicate thresholds; empty range when t[j-1] == t[j]).
    //    Thresholds are integer-valued floats, so (int) conversion is exact.
    {
        const int  sign = signs[c];
        const int  j    = tid;                 // 0..255
        const float tjf = (j < NTH) ? thresholds[c * NTH + j] : 193.0f;
        const float tpf = (j > 0)   ? thresholds[c * NTH + j - 1] : -193.0f;
        const int   tj  = (int)tjf;
        const int   tp  = (int)tpf;
        const int   qlo = max(tp + 1, -192);
        const int   qhi = min(tj, 192);
        const float val = (float)(sign > 0 ? j : (NTH - j));
        for (int q = qlo; q <= qhi; ++q) lut[q + 192] = val;
    }
    __syncthreads();

    // 3) Lookup + non-temporal store (output is write-once).
    #define LOOKUP(f) lut[(int)fminf(fmaxf(floorf(f), -192.0f), 192.0f) + 192]
    vfloat4 r0, r1, r2;
    r0.x = LOOKUP(v0.x); r0.y = LOOKUP(v0.y); r0.z = LOOKUP(v0.z); r0.w = LOOKUP(v0.w);
    r1.x = LOOKUP(v1.x); r1.y = LOOKUP(v1.y); r1.z = LOOKUP(v1.z); r1.w = LOOKUP(v1.w);
    r2.x = LOOKUP(v2.x); r2.y = LOOKUP(v2.y); r2.z = LOOKUP(v2.z); r2.w = LOOKUP(v2.w);
    __builtin_nontemporal_store(r0, &ov[tid]);
    __builtin_nontemporal_store(r1, &ov[tid + 256]);
    __builtin_nontemporal_store(r2, &ov[tid + 512]);

    if (tid < 16) {
        vfloat4 r3;
        r3.x = LOOKUP(v3.x); r3.y = LOOKUP(v3.y); r3.z = LOOKUP(v3.z); r3.w = LOOKUP(v3.w);
        __builtin_nontemporal_store(r3, &ov[tid + 768]);
    }
    #undef LOOKUP
}

extern "C" void kernel_launch(void* const* d_in, const int* in_sizes, int n_in,
                              void* d_out, int out_size, void* d_ws, size_t ws_size,
                              hipStream_t stream) {
    const float* x          = (const float*)d_in[0];
    const float* thresholds = (const float*)d_in[1];
    const int*   signs      = (const int*)d_in[2];
    float*       out        = (float*)d_out;

    // 8*64 = 512 blocks, one (b,c) slice of 3136 elements each.
    stq4d_kernel<<<512, 256, 0, stream>>>(x, thresholds, signs, out);
}